// Round 10
// baseline (155.844 us; speedup 1.0000x reference)
//
#include <hip/hip_runtime.h>
#include <hip/hip_bf16.h>
#include <stdint.h>

// SimpleVectorQuantizer: vecs [16,32,128,64] f32, codebook [512,64] f32.
// Outputs (flat f32): vecs_hat [65536*64], z [65536] (as float), l_commit, l_codebook.
//
// Round 10: r9's occupancy+chain fixes with LEGAL LDS. r9 crashed: 73 KB of
// static __shared__ exceeds the 64 KB per-workgroup cap (160 KiB is the CU
// pool, not one block's allowance). Back to 4 staging phases (34.8 KB tile,
// 38.4 KB total static LDS); keep 8-wave blocks / MT=1 (4 waves/SIMD at
// 2 blocks/CU), split 3+3 MFMA chains, csq-2e ranking (vsq only in loss;
// rescue computes the exact ref-rounded score — the absmax-0-proven path).

#define VQ_K 64
#define VQ_S 512
#define NTHREADS 512                     // 8 waves
#define VPB 128                          // vectors per block (8 waves x 16)
#define PHASES 4
#define NT_PER_PHASE 8                   // 8 n-tiles of 16 codewords per phase
#define ROWB 272                         // B row: 64 hi bf16 + 64 lo bf16 + 16 pad
#define PHASE_BYTES (NT_PER_PHASE * 16 * ROWB)   // 34816
#define PHASE_F4 (PHASE_BYTES / 16)              // 2176
#define CSQ_OFF (VQ_S * ROWB)            // 139264
#define CELL 7.62939453125e-6f           // f32 ulp at ref-score magnitude ~64
#define GAP_THRESH (8.0f * CELL)

typedef __attribute__((ext_vector_type(8))) short bf16x8;
typedef __attribute__((ext_vector_type(4))) float f32x4;

static __device__ __forceinline__ unsigned short f2bf_rne(float f) {
    unsigned u = __float_as_uint(f);
    unsigned r = (u + 0x7fffu + ((u >> 16) & 1u)) >> 16;
    return (unsigned short)r;
}
static __device__ __forceinline__ float bf2f(unsigned short h) {
    return __uint_as_float(((unsigned)h) << 16);
}

// K1: one wave per codebook row; lane k handles element k. Also zeroes loss.
__global__ __launch_bounds__(256, 1) void vq_prep(
    const float* __restrict__ cb, unsigned char* __restrict__ bimg,
    float* __restrict__ out_loss) {
    if (blockIdx.x == 0 && threadIdx.x == 0) { out_loss[0] = 0.f; out_loss[1] = 0.f; }
    const int lane = threadIdx.x & 63;
    const int row = blockIdx.x * 4 + (threadIdx.x >> 6);
    float c = cb[(size_t)row * VQ_K + lane];
    double d = (double)c * (double)c;
#pragma unroll
    for (int off = 1; off <= 32; off <<= 1) d += __shfl_xor(d, off, 64);
    unsigned short hi = f2bf_rne(c);
    unsigned short lo = f2bf_rne(c - bf2f(hi));
    unsigned char* rowp = bimg + (size_t)row * ROWB;
    ((unsigned short*)rowp)[lane] = hi;
    ((unsigned short*)(rowp + 128))[lane] = lo;
    if (lane == 0) ((float*)(bimg + CSQ_OFF))[row] = (float)d;
}

// K2: MFMA scan + in-block exact rescue. 8 waves x 1 m-tile = 128 vectors.
__global__ __launch_bounds__(NTHREADS, 4) void vq_mfma(
    const float* __restrict__ vecs, const float* __restrict__ codebook,
    const unsigned char* __restrict__ bimg,
    float* __restrict__ out_hat, float* __restrict__ out_z,
    float* __restrict__ out_loss, float inv_n) {
    __shared__ unsigned char ldsB[PHASE_BYTES];   // 34816 B
    __shared__ float csq_sh[VQ_S];                // 2 KB
    __shared__ float vsq_all[VPB];
    __shared__ int zsh[VPB];
    __shared__ int rlist[VPB];
    __shared__ int rn;
    __shared__ float loss_sh;

    const int tid = threadIdx.x;
    const int wave = tid >> 6;                    // 0..7
    const int lane = tid & 63;
    const int m = lane & 15;
    const int q = lane >> 4;
    const int blockbase = blockIdx.x * VPB;
    const int wavebase = blockbase + wave * 16;   // 16 vectors per wave

    if (tid == 0) { rn = 0; loss_sh = 0.f; }

    // ---- A fragment (bf16 split) + exact vsq for this wave's 16 vectors ----
    bf16x8 ah1, ah2, al1, al2;
    {
        const float* vp = vecs + (size_t)(wavebase + m) * VQ_K + q * 8;
        float4 a0 = ((const float4*)vp)[0];
        float4 a1 = ((const float4*)vp)[1];
        float4 b0 = ((const float4*)(vp + 32))[0];
        float4 b1 = ((const float4*)(vp + 32))[1];
        float w1[8] = {a0.x, a0.y, a0.z, a0.w, a1.x, a1.y, a1.z, a1.w};
        float w2[8] = {b0.x, b0.y, b0.z, b0.w, b1.x, b1.y, b1.z, b1.w};
        double p = 0.0;
#pragma unroll
        for (int j = 0; j < 8; ++j) {
            double d1 = (double)w1[j], d2 = (double)w2[j];
            p = fma(d1, d1, p); p = fma(d2, d2, p);
        }
        p += __shfl_xor(p, 16, 64);
        p += __shfl_xor(p, 32, 64);
        if (q == 0) vsq_all[wave * 16 + m] = (float)p;
#pragma unroll
        for (int j = 0; j < 8; ++j) {
            unsigned short h1 = f2bf_rne(w1[j]);
            unsigned short h2 = f2bf_rne(w2[j]);
            ah1[j] = (short)h1;
            ah2[j] = (short)h2;
            al1[j] = (short)f2bf_rne(w1[j] - bf2f(h1));
            al2[j] = (short)f2bf_rne(w2[j] - bf2f(h2));
        }
    }

    // 4 states per lane: rows q*4+r of this wave's tile, across all 512 cols.
    float t1s[4], t2s[4];
    int t1i[4];
#pragma unroll
    for (int st = 0; st < 4; ++st) { t1s[st] = 3.4e38f; t2s[st] = 3.4e38f; t1i[st] = 0; }
    const f32x4 zero4 = {0.f, 0.f, 0.f, 0.f};
    const unsigned char* ldsrow = ldsB + m * ROWB + q * 16;

    for (int p = 0; p < PHASES; ++p) {
        __syncthreads();
        {
            const float4* src = (const float4*)(bimg + (size_t)p * PHASE_BYTES);
            float4* dst = (float4*)ldsB;
#pragma unroll
            for (int j = 0; j < 5; ++j) {
                int i = tid + j * NTHREADS;
                if (i < PHASE_F4) dst[i] = src[i];
            }
            if (p == 0 && tid < 128)
                ((float4*)csq_sh)[tid] = ((const float4*)(bimg + CSQ_OFF))[tid];
        }
        __syncthreads();

#pragma unroll
        for (int t = 0; t < NT_PER_PHASE; ++t) {
            const int nbase = p * 128 + t * 16;
            const float csqn = csq_sh[nbase + m];
            const int nidx = nbase + m;
            const unsigned char* rb = ldsrow + t * 16 * ROWB;
            bf16x8 bh1 = *(const bf16x8*)(rb);
            bf16x8 bh2 = *(const bf16x8*)(rb + 64);
            bf16x8 bl1 = *(const bf16x8*)(rb + 128);
            bf16x8 bl2 = *(const bf16x8*)(rb + 192);
            // Two independent 3-chains (k-window 1 and 2), summed at use.
            f32x4 accA = __builtin_amdgcn_mfma_f32_16x16x32_bf16(ah1, bh1, zero4, 0, 0, 0);
            f32x4 accB = __builtin_amdgcn_mfma_f32_16x16x32_bf16(ah2, bh2, zero4, 0, 0, 0);
            accA = __builtin_amdgcn_mfma_f32_16x16x32_bf16(ah1, bl1, accA, 0, 0, 0);
            accB = __builtin_amdgcn_mfma_f32_16x16x32_bf16(ah2, bl2, accB, 0, 0, 0);
            accA = __builtin_amdgcn_mfma_f32_16x16x32_bf16(al1, bh1, accA, 0, 0, 0);
            accB = __builtin_amdgcn_mfma_f32_16x16x32_bf16(al2, bh2, accB, 0, 0, 0);
#pragma unroll
            for (int r = 0; r < 4; ++r) {
                // Rank on partial = csq - 2e (vsq constant per row; added for loss).
                float sc = fmaf(-2.0f, accA[r], fmaf(-2.0f, accB[r], csqn));
                bool b1 = sc < t1s[r];
                bool b2 = sc < t2s[r];
                t2s[r] = b1 ? t1s[r] : (b2 ? sc : t2s[r]);
                t1s[r] = b1 ? sc : t1s[r];
                t1i[r] = b1 ? nidx : t1i[r];
            }
        }
    }

    // ---- butterfly merge over the 16 n-columns ----
    unsigned long long pk[4];
#pragma unroll
    for (int st = 0; st < 4; ++st) {
        unsigned u = __float_as_uint(t1s[st]);
        unsigned mono = (u & 0x80000000u) ? ~u : (u | 0x80000000u);
        pk[st] = ((unsigned long long)mono << 32) | (unsigned)t1i[st];
    }
#pragma unroll
    for (int dd = 1; dd <= 8; dd <<= 1) {
#pragma unroll
        for (int st = 0; st < 4; ++st) {
            unsigned long long opk = __shfl_xor(pk[st], dd, 64);
            float o1 = __shfl_xor(t1s[st], dd, 64);
            float o2 = __shfl_xor(t2s[st], dd, 64);
            t2s[st] = fminf(fmaxf(t1s[st], o1), fminf(t2s[st], o2));
            t1s[st] = fminf(t1s[st], o1);
            pk[st] = opk < pk[st] ? opk : pk[st];
        }
    }

    // ---- writers: lanes m<4 own state r=m -> vector row q*4+m ----
    float w1s = 3.4e38f, w2s = 3.4e38f;
    unsigned long long wpk = 0;
#pragma unroll
    for (int i = 0; i < 4; ++i) {
        bool sel = (m == i);
        w1s = sel ? t1s[i] : w1s;
        w2s = sel ? t2s[i] : w2s;
        wpk = sel ? pk[i] : wpk;
    }
    const bool writer = (m < 4);
    const int vloc = wave * 16 + q * 4 + (m & 3);
    float dl = 0.f;
    if (writer) {
        zsh[vloc] = (int)(wpk & 0xffffffffull);
        if (w2s - w1s <= GAP_THRESH) {
            int pos = atomicAdd(&rn, 1);
            rlist[pos] = vloc;
        }
        float full = vsq_all[vloc] + w1s;          // loss uses vsq + best
        dl = (full < 0.f ? 0.f : full) * inv_n;
    }
#pragma unroll
    for (int off = 32; off >= 1; off >>= 1) dl += __shfl_down(dl, off, 64);
    if (lane == 0) atomicAdd(&loss_sh, dl);

    __syncthreads();

    // ---- in-block exact rescue: wave w handles rlist[base+w] ----
    const int nr = rn;
    for (int base = 0; base < nr; base += 8) {
        const int slot = base + wave;
        if (slot < nr) {                       // wave-uniform
            const int rv = rlist[slot];
            const float4* vrow4 = (const float4*)(vecs + (size_t)(blockbase + rv) * VQ_K);
            const float vsqr = vsq_all[rv];
            unsigned long long best = ~0ull;
            for (int j = 0; j < 8; ++j) {
                const int s = lane * 8 + j;
                const float4* crow = (const float4*)(codebook + (size_t)s * VQ_K);
                double acc = 0.0;
#pragma unroll
                for (int qq = 0; qq < VQ_K / 4; ++qq) {
                    float4 c = crow[qq];
                    float4 t = vrow4[qq];      // wave-uniform -> scalar loads
                    acc = fma((double)c.x, (double)t.x, acc);
                    acc = fma((double)c.y, (double)t.y, acc);
                    acc = fma((double)c.z, (double)t.z, acc);
                    acc = fma((double)c.w, (double)t.w, acc);
                }
                float e = (float)acc;
                float sc = fmaf(-2.0f, e, vsqr) + csq_sh[s];   // exact ref rounding
                unsigned u = __float_as_uint(sc);
                unsigned mono = (u & 0x80000000u) ? ~u : (u | 0x80000000u);
                unsigned long long pkr = ((unsigned long long)mono << 32) | (unsigned)s;
                best = pkr < best ? pkr : best;
            }
#pragma unroll
            for (int off = 32; off >= 1; off >>= 1) {
                unsigned long long o = __shfl_down(best, off, 64);
                best = o < best ? o : best;
            }
            if (lane == 0) zsh[rv] = (int)(best & 0xffffffffull);
        }
    }
    __syncthreads();

    // ---- loss atomics (2 per block), coalesced z write + gather ----
    if (tid == 0) {
        float l = loss_sh;
        atomicAdd(&out_loss[0], l);
        atomicAdd(&out_loss[1], l);
    }
    if (tid < VPB) out_z[blockbase + tid] = (float)zsh[tid];
    const float4* cb4 = (const float4*)codebook;
    float4* hat4 = (float4*)(out_hat + (size_t)blockbase * VQ_K);
    const int F = VPB * (VQ_K / 4);                // 2048
#pragma unroll
    for (int f = tid; f < F; f += NTHREADS) {
        int vv = f >> 4;
        int k4 = f & 15;
        hat4[f] = cb4[zsh[vv] * (VQ_K / 4) + k4];
    }
}

extern "C" void kernel_launch(void* const* d_in, const int* in_sizes, int n_in,
                              void* d_out, int out_size, void* d_ws, size_t ws_size,
                              hipStream_t stream) {
    const float* vecs = (const float*)d_in[0];
    const float* codebook = (const float*)d_in[1];
    float* out = (float*)d_out;

    const int nvec = in_sizes[0] / VQ_K;            // 65536
    unsigned char* bimg = (unsigned char*)d_ws;     // 141312 B image

    float* out_hat = out;
    float* out_z = out + (size_t)nvec * VQ_K;
    float* out_loss = out + out_size - 2;

    vq_prep<<<VQ_S / 4, 256, 0, stream>>>(codebook, bimg, out_loss);
    vq_mfma<<<nvec / VPB, NTHREADS, 0, stream>>>(
        vecs, codebook, bimg, out_hat, out_z, out_loss, 1.0f / (float)nvec);
}

// Round 11
// 112.621 us; speedup vs baseline: 1.3838x; 1.3838x over previous
//
#include <hip/hip_runtime.h>
#include <hip/hip_bf16.h>
#include <stdint.h>

// SimpleVectorQuantizer: vecs [16,32,128,64] f32, codebook [512,64] f32.
// Outputs (flat f32): vecs_hat [65536*64], z [65536] (as float), l_commit, l_codebook.
//
// Round 11: barrier-free streaming scan. r6-r10 showed the staged-LDS loop is
// latency-bound (pipes <16%) at any reachable occupancy, and tight
// launch_bounds caused catastrophic spills (r10: WRITE 171 MB, VGPR 64).
// Now: B fragments stream straight from L2 (139 KB image, hot), software-
// pipelined 1 tile ahead, NO barrier in the K-loop. -csq/2 is folded into the
// MFMA C operand so the ranking key is just accA+accB (maximized). Merge /
// writer / in-block exact-f64 rescue / gather are the r8/r10-proven absmax-0
// path. launch_bounds(256,2): loose 256-VGPR cap, no forced spill.

#define VQ_K 64
#define VQ_S 512
#define NTHREADS 256                     // 4 waves
#define MT 2                             // m-tiles per wave -> 32 vectors/wave
#define VPB 128                          // vectors per block
#define NTILES 32                        // 512 codewords / 16 per tile
#define ROWB 272                         // B row: 64 hi bf16 + 64 lo bf16 + 16 pad
#define TILE_STRIDE (16 * ROWB)          // 4352 B
#define CSQ_OFF (VQ_S * ROWB)            // 139264
#define CELL 7.62939453125e-6f           // f32 ulp at ref-score magnitude ~64
#define GAP_THRESH (8.0f * CELL)

typedef __attribute__((ext_vector_type(8))) short bf16x8;
typedef __attribute__((ext_vector_type(4))) float f32x4;

static __device__ __forceinline__ unsigned short f2bf_rne(float f) {
    unsigned u = __float_as_uint(f);
    unsigned r = (u + 0x7fffu + ((u >> 16) & 1u)) >> 16;
    return (unsigned short)r;
}
static __device__ __forceinline__ float bf2f(unsigned short h) {
    return __uint_as_float(((unsigned)h) << 16);
}

// K1: one wave per codebook row; lane k handles element k. Also zeroes loss.
__global__ __launch_bounds__(256, 1) void vq_prep(
    const float* __restrict__ cb, unsigned char* __restrict__ bimg,
    float* __restrict__ out_loss) {
    if (blockIdx.x == 0 && threadIdx.x == 0) { out_loss[0] = 0.f; out_loss[1] = 0.f; }
    const int lane = threadIdx.x & 63;
    const int row = blockIdx.x * 4 + (threadIdx.x >> 6);
    float c = cb[(size_t)row * VQ_K + lane];
    double d = (double)c * (double)c;
#pragma unroll
    for (int off = 1; off <= 32; off <<= 1) d += __shfl_xor(d, off, 64);
    unsigned short hi = f2bf_rne(c);
    unsigned short lo = f2bf_rne(c - bf2f(hi));
    unsigned char* rowp = bimg + (size_t)row * ROWB;
    ((unsigned short*)rowp)[lane] = hi;
    ((unsigned short*)(rowp + 128))[lane] = lo;
    if (lane == 0) ((float*)(bimg + CSQ_OFF))[row] = (float)d;
}

// K2: streaming MFMA scan + in-block exact rescue. 4 waves x 2 m-tiles.
__global__ __launch_bounds__(NTHREADS, 2) void vq_mfma(
    const float* __restrict__ vecs, const float* __restrict__ codebook,
    const unsigned char* __restrict__ bimg,
    float* __restrict__ out_hat, float* __restrict__ out_z,
    float* __restrict__ out_loss, float inv_n) {
    __shared__ float csq_sh[VQ_S];       // exact csq (rescue)
    __shared__ float csqn2_sh[VQ_S];     // -csq/2 (C-init for the scan)
    __shared__ float vsq_all[VPB];
    __shared__ int zsh[VPB];
    __shared__ int rlist[VPB];
    __shared__ int rn;
    __shared__ float loss_sh;

    const int tid = threadIdx.x;
    const int wave = tid >> 6;                    // 0..3
    const int lane = tid & 63;
    const int m = lane & 15;
    const int q = lane >> 4;
    const int blockbase = blockIdx.x * VPB;
    const int wavebase = blockbase + wave * 32;   // 32 vectors per wave

    if (tid == 0) { rn = 0; loss_sh = 0.f; }
    // Stage csq tables once (only barrier before the free-running loop).
    {
        const float* csqg = (const float*)(bimg + CSQ_OFF);
#pragma unroll
        for (int i = tid; i < VQ_S; i += NTHREADS) {
            float c = csqg[i];
            csq_sh[i] = c;
            csqn2_sh[i] = -0.5f * c;
        }
    }

    // ---- A fragments (bf16 split) + exact vsq ----
    bf16x8 ah1[MT], ah2[MT], al1[MT], al2[MT];
#pragma unroll
    for (int mt = 0; mt < MT; ++mt) {
        const float* vp = vecs + (size_t)(wavebase + mt * 16 + m) * VQ_K + q * 8;
        float4 a0 = ((const float4*)vp)[0];
        float4 a1 = ((const float4*)vp)[1];
        float4 b0 = ((const float4*)(vp + 32))[0];
        float4 b1 = ((const float4*)(vp + 32))[1];
        float w1[8] = {a0.x, a0.y, a0.z, a0.w, a1.x, a1.y, a1.z, a1.w};
        float w2[8] = {b0.x, b0.y, b0.z, b0.w, b1.x, b1.y, b1.z, b1.w};
        double p = 0.0;
#pragma unroll
        for (int j = 0; j < 8; ++j) {
            double d1 = (double)w1[j], d2 = (double)w2[j];
            p = fma(d1, d1, p); p = fma(d2, d2, p);
        }
        p += __shfl_xor(p, 16, 64);
        p += __shfl_xor(p, 32, 64);
        if (q == 0) vsq_all[wave * 32 + mt * 16 + m] = (float)p;
#pragma unroll
        for (int j = 0; j < 8; ++j) {
            unsigned short h1 = f2bf_rne(w1[j]);
            unsigned short h2 = f2bf_rne(w2[j]);
            ah1[mt][j] = (short)h1;
            ah2[mt][j] = (short)h2;
            al1[mt][j] = (short)f2bf_rne(w1[j] - bf2f(h1));
            al2[mt][j] = (short)f2bf_rne(w2[j] - bf2f(h2));
        }
    }
    __syncthreads();

    // ---- streaming K-loop: no barriers, 1-tile software pipeline ----
    // u-state tracks MAX of accA+accB (= e6 - csq/2); sc = -2u.
    float t1u[8], t2u[8];
    int t1i[8];
#pragma unroll
    for (int st = 0; st < 8; ++st) { t1u[st] = -3.4e38f; t2u[st] = -3.4e38f; t1i[st] = 0; }
    const f32x4 zero4 = {0.f, 0.f, 0.f, 0.f};

    const char* bp = (const char*)bimg + m * ROWB + q * 16;
    bf16x8 cb1 = *(const bf16x8*)(bp);
    bf16x8 cb2 = *(const bf16x8*)(bp + 64);
    bf16x8 cb3 = *(const bf16x8*)(bp + 128);
    bf16x8 cb4 = *(const bf16x8*)(bp + 192);

#pragma unroll 4
    for (int t = 0; t < NTILES; ++t) {
        // prefetch next tile (t=31 reads the csq tail — in-bounds junk, unused)
        const char* np = bp + TILE_STRIDE;
        bf16x8 nb1 = *(const bf16x8*)(np);
        bf16x8 nb2 = *(const bf16x8*)(np + 64);
        bf16x8 nb3 = *(const bf16x8*)(np + 128);
        bf16x8 nb4 = *(const bf16x8*)(np + 192);

        const float mh = csqn2_sh[t * 16 + m];
        const f32x4 ci = {mh, mh, mh, mh};
        const int nidx = t * 16 + m;
#pragma unroll
        for (int mt = 0; mt < MT; ++mt) {
            f32x4 accA = __builtin_amdgcn_mfma_f32_16x16x32_bf16(ah1[mt], cb1, zero4, 0, 0, 0);
            f32x4 accB = __builtin_amdgcn_mfma_f32_16x16x32_bf16(ah2[mt], cb2, ci, 0, 0, 0);
            accA = __builtin_amdgcn_mfma_f32_16x16x32_bf16(al1[mt], cb1, accA, 0, 0, 0);
            accB = __builtin_amdgcn_mfma_f32_16x16x32_bf16(al2[mt], cb2, accB, 0, 0, 0);
            accA = __builtin_amdgcn_mfma_f32_16x16x32_bf16(ah1[mt], cb3, accA, 0, 0, 0);
            accB = __builtin_amdgcn_mfma_f32_16x16x32_bf16(ah2[mt], cb4, accB, 0, 0, 0);
#pragma unroll
            for (int r = 0; r < 4; ++r) {
                const int st = mt * 4 + r;
                float u = accA[r] + accB[r];
                bool gt = u > t1u[st];                          // strict: first index wins
                t2u[st] = fminf(fmaxf(u, t2u[st]), t1u[st]);    // 2nd-largest
                t1u[st] = fmaxf(t1u[st], u);
                t1i[st] = gt ? nidx : t1i[st];
            }
        }
        cb1 = nb1; cb2 = nb2; cb3 = nb3; cb4 = nb4;
        bp = np;
    }

    // ---- convert to score space (sc = -2u) and butterfly-merge 16 columns ----
    float t1s[8], t2s[8];
    unsigned long long pk[8];
#pragma unroll
    for (int st = 0; st < 8; ++st) {
        t1s[st] = -2.0f * t1u[st];
        t2s[st] = -2.0f * t2u[st];
        unsigned u = __float_as_uint(t1s[st]);
        unsigned mono = (u & 0x80000000u) ? ~u : (u | 0x80000000u);
        pk[st] = ((unsigned long long)mono << 32) | (unsigned)t1i[st];
    }
#pragma unroll
    for (int dd = 1; dd <= 8; dd <<= 1) {
#pragma unroll
        for (int st = 0; st < 8; ++st) {
            unsigned long long opk = __shfl_xor(pk[st], dd, 64);
            float o1 = __shfl_xor(t1s[st], dd, 64);
            float o2 = __shfl_xor(t2s[st], dd, 64);
            t2s[st] = fminf(fmaxf(t1s[st], o1), fminf(t2s[st], o2));
            t1s[st] = fminf(t1s[st], o1);
            pk[st] = opk < pk[st] ? opk : pk[st];
        }
    }

    // ---- writers: lanes m<8 own state st=m -> vector wave*32+(m>>2)*16+q*4+(m&3)
    float w1s = 3.4e38f, w2s = 3.4e38f;
    unsigned long long wpk = 0;
#pragma unroll
    for (int i = 0; i < 8; ++i) {
        bool sel = (m == i);
        w1s = sel ? t1s[i] : w1s;
        w2s = sel ? t2s[i] : w2s;
        wpk = sel ? pk[i] : wpk;
    }
    const bool writer = (m < 8);
    const int vloc = wave * 32 + ((m >> 2) & 1) * 16 + q * 4 + (m & 3);
    float dl = 0.f;
    if (writer) {
        zsh[vloc] = (int)(wpk & 0xffffffffull);
        if (w2s - w1s <= GAP_THRESH) {
            int pos = atomicAdd(&rn, 1);
            rlist[pos] = vloc;
        }
        float full = vsq_all[vloc] + w1s;          // loss = relu(vsq + best)
        dl = (full < 0.f ? 0.f : full) * inv_n;
    }
#pragma unroll
    for (int off = 32; off >= 1; off >>= 1) dl += __shfl_down(dl, off, 64);
    if (lane == 0) atomicAdd(&loss_sh, dl);

    __syncthreads();

    // ---- in-block exact rescue (r3-proven arithmetic): wave w -> rlist[base+w]
    const int nr = rn;
    for (int base = 0; base < nr; base += 4) {
        const int slot = base + wave;
        if (slot < nr) {                       // wave-uniform
            const int rv = rlist[slot];
            const float4* vrow4 = (const float4*)(vecs + (size_t)(blockbase + rv) * VQ_K);
            const float vsqr = vsq_all[rv];
            unsigned long long best = ~0ull;
            for (int j = 0; j < 8; ++j) {
                const int s = lane * 8 + j;
                const float4* crow = (const float4*)(codebook + (size_t)s * VQ_K);
                double acc = 0.0;
#pragma unroll
                for (int qq = 0; qq < VQ_K / 4; ++qq) {
                    float4 c = crow[qq];
                    float4 tt = vrow4[qq];     // wave-uniform -> scalar loads
                    acc = fma((double)c.x, (double)tt.x, acc);
                    acc = fma((double)c.y, (double)tt.y, acc);
                    acc = fma((double)c.z, (double)tt.z, acc);
                    acc = fma((double)c.w, (double)tt.w, acc);
                }
                float e = (float)acc;
                float sc = fmaf(-2.0f, e, vsqr) + csq_sh[s];   // exact ref rounding
                unsigned u = __float_as_uint(sc);
                unsigned mono = (u & 0x80000000u) ? ~u : (u | 0x80000000u);
                unsigned long long pkr = ((unsigned long long)mono << 32) | (unsigned)s;
                best = pkr < best ? pkr : best;
            }
#pragma unroll
            for (int off = 32; off >= 1; off >>= 1) {
                unsigned long long o = __shfl_down(best, off, 64);
                best = o < best ? o : best;
            }
            if (lane == 0) zsh[rv] = (int)(best & 0xffffffffull);
        }
    }
    __syncthreads();

    // ---- loss atomics (2/block), coalesced z write + gather ----
    if (tid == 0) {
        float l = loss_sh;
        atomicAdd(&out_loss[0], l);
        atomicAdd(&out_loss[1], l);
    }
    if (tid < VPB) out_z[blockbase + tid] = (float)zsh[tid];
    const float4* cb4g = (const float4*)codebook;
    float4* hat4 = (float4*)(out_hat + (size_t)blockbase * VQ_K);
    const int F = VPB * (VQ_K / 4);                // 2048
#pragma unroll
    for (int f = tid; f < F; f += NTHREADS) {
        int vv = f >> 4;
        int k4 = f & 15;
        hat4[f] = cb4g[zsh[vv] * (VQ_K / 4) + k4];
    }
}

extern "C" void kernel_launch(void* const* d_in, const int* in_sizes, int n_in,
                              void* d_out, int out_size, void* d_ws, size_t ws_size,
                              hipStream_t stream) {
    const float* vecs = (const float*)d_in[0];
    const float* codebook = (const float*)d_in[1];
    float* out = (float*)d_out;

    const int nvec = in_sizes[0] / VQ_K;            // 65536
    unsigned char* bimg = (unsigned char*)d_ws;     // 141312 B image (+ slack)

    float* out_hat = out;
    float* out_z = out + (size_t)nvec * VQ_K;
    float* out_loss = out + out_size - 2;

    vq_prep<<<VQ_S / 4, 256, 0, stream>>>(codebook, bimg, out_loss);
    vq_mfma<<<nvec / VPB, NTHREADS, 0, stream>>>(
        vecs, codebook, bimg, out_hat, out_z, out_loss, 1.0f / (float)nvec);
}